// Round 8
// baseline (245.148 us; speedup 1.0000x reference)
//
#include <hip/hip_runtime.h>
#include <stdint.h>

typedef __attribute__((ext_vector_type(8)))  short    short8;
typedef __attribute__((ext_vector_type(16))) float    f32x16;
typedef __attribute__((ext_vector_type(4)))  float    f32x4;
typedef __attribute__((ext_vector_type(4)))  uint32_t u32x4;

// net -> gas id (0..5)
__device__ __constant__ int8_t g_gas[76] = {
  0,0,0,0,0,0,0,0,0,0,0,0,0,0,0,0,0,0,0,0,0,0,0,0,0,0,0,0,0,
  1,1,1,1,1,1,1,1,1,1,1,1,1,
  2,2,2,2,2,2,2,2,2,
  3,3,3,
  4,4,4,4,4,4,4,4,4,
  5,5,5,5,5,5,5,5,5,5,5,5,5
};
// net -> first channel, second channel (-1 = none). Inverse of the SELECT tree.
__device__ __constant__ int8_t g_ch0[76] = {
  0,2,3,4,5,6,7,8,9,10,11,12,13,14,15,16,17,18,19,20,21,22,23,24,25,26,27,28,29,
  0,2,3,18,19,20,21,22,23,26,27,28,29,
  0,2,3,6,7,10,11,14,15,
  0,2,3,
  0,2,3,4,5,8,9,12,13,
  0,2,3,16,17,18,19,20,21,22,23,28,29
};
__device__ __constant__ int8_t g_ch1[76] = {
  1,-1,-1,-1,-1,-1,-1,-1,-1,-1,-1,-1,-1,-1,-1,-1,-1,-1,-1,-1,-1,-1,-1,-1,-1,-1,-1,-1,-1,
  1,-1,-1,-1,-1,-1,-1,-1,-1,-1,-1,-1,-1,
  1,-1,-1,-1,-1,-1,-1,-1,-1,
  1,-1,-1,
  1,-1,-1,-1,-1,-1,-1,-1,-1,
  1,-1,-1,-1,-1,-1,-1,-1,-1,-1,-1,-1,-1
};

// packed f32x2 -> bf16x2 (RTNE), single VALU instruction. Low half = a.
__device__ inline uint32_t cvtpk(float a, float b) {
  uint32_t r;
  asm("v_cvt_pk_bf16_f32 %0, %1, %2" : "=v"(r) : "v"(a), "v"(b));
  return r;
}

// ---------------------------------------------------------------------------
// Prep: split W2 into hi/lo bf16 and lay out as 32x32x16 A-fragments (W2^T).
// Layout: w2f[((term*2 + T)*4 + s)*64 + lane] (u32x4 units), per net i.
//   lane l: m = (l&31) + 32*T,  k = 4*(l>>5) + {0,1,2,3,8,9,10,11} + 16*s
// ---------------------------------------------------------------------------
__global__ __launch_bounds__(256) void prep_w2(const float* __restrict__ W2,
                                               u32x4* __restrict__ w2f)
{
  const int i   = blockIdx.x;
  const int tid = threadIdx.x;
  const int l   = tid & 63;
  const int T   = (tid >> 6) & 1;
  const int sh  = tid >> 7;          // 0,1
  const int h   = l >> 5;
  const int m   = (l & 31) + 32 * T;
  const float* __restrict__ w2 = W2 + i * 4096;   // [k][m] row-major
  u32x4* __restrict__ dst = w2f + (size_t)i * 1024;

#pragma unroll
  for (int ss = 0; ss < 2; ++ss) {
    const int s  = sh * 2 + ss;
    const int kb = 4 * h + 16 * s;
    float x[8];
#pragma unroll
    for (int j = 0; j < 4; ++j) x[j]     = w2[(kb + j) * 64 + m];
#pragma unroll
    for (int j = 0; j < 4; ++j) x[4 + j] = w2[(kb + 8 + j) * 64 + m];
    u32x4 hv, lv;
#pragma unroll
    for (int w = 0; w < 4; ++w) {
      float a = x[2 * w], b = x[2 * w + 1];
      uint32_t hp = cvtpk(a, b);
      float fa = __builtin_bit_cast(float, hp << 16);
      float fb = __builtin_bit_cast(float, hp & 0xffff0000u);
      hv[w] = hp;
      lv[w] = cvtpk(a - fa, b - fb);
    }
    dst[((0 * 2 + T) * 4 + s) * 64 + l] = hv;
    dst[((1 * 2 + T) * 4 + s) * 64 + l] = lv;
  }
}

// ---------------------------------------------------------------------------
// Fused MLP + channel combine, software-pipelined.
// Block: 256 thr = 4 waves, ALL on the same net i; wave w owns rows
// rowBase + w*32 + (0..31). A-fragments for net i live in LDS (16 KB),
// double-buffered; net i+1's fragments are global-loaded into registers at
// the top of iter i and ds_written after the epilogue (latency hidden).
// Grid = B/128 = 256 blocks (1 per CU).
// ---------------------------------------------------------------------------
__global__ __launch_bounds__(256, 1) void fused_mlp(
    const float* __restrict__ t_p,  const float* __restrict__ comp,
    const float* __restrict__ null_lw, const float* __restrict__ null_iw,
    const float* __restrict__ W1,   const float* __restrict__ b1,
    const float* __restrict__ b2,   const float* __restrict__ W3,
    const float* __restrict__ b3,
    const float* __restrict__ W_lw, const float* __restrict__ b_lw,
    const float* __restrict__ W_iw, const float* __restrict__ b_iw,
    const u32x4* __restrict__ w2f,
    float* __restrict__ out, int B)
{
  __shared__ u32x4 a_lds[2][1024];    // 32 KB double-buffered A-fragments
  __shared__ float chan[30][128];     // 15 KB channel accumulators

  const int tid = threadIdx.x;
  const int l   = tid & 63;
  const int w   = tid >> 6;           // wave id = row-tile
  const int h   = l >> 5;
  const int ln  = l & 31;
  const int rowBase = blockIdx.x * 128;
  const int row = rowBase + w * 32 + ln;

  for (int k = tid; k < 30 * 128; k += 256) ((float*)chan)[k] = 0.f;

  const float2 tp = reinterpret_cast<const float2*>(t_p)[row];

  // ---- prologue: stage net 0's A-fragments (wave w loads slots 4w..4w+3)
  {
    u32x4 s0 = w2f[(4 * w + 0) * 64 + l];
    u32x4 s1 = w2f[(4 * w + 1) * 64 + l];
    u32x4 s2 = w2f[(4 * w + 2) * 64 + l];
    u32x4 s3 = w2f[(4 * w + 3) * 64 + l];
    a_lds[0][(4 * w + 0) * 64 + l] = s0;
    a_lds[0][(4 * w + 1) * 64 + l] = s1;
    a_lds[0][(4 * w + 2) * 64 + l] = s2;
    a_lds[0][(4 * w + 3) * 64 + l] = s3;
  }
  __syncthreads();

  for (int i = 0; i < 76; ++i) {
    const int cur = i & 1;

    // ---- prefetch net i+1's A-fragments into registers (no wait here)
    u32x4 st0, st1, st2, st3;
    if (i < 75) {
      const u32x4* __restrict__ pn = w2f + (size_t)(i + 1) * 1024;
      st0 = pn[(4 * w + 0) * 64 + l];
      st1 = pn[(4 * w + 1) * 64 + l];
      st2 = pn[(4 * w + 2) * 64 + l];
      st3 = pn[(4 * w + 3) * 64 + l];
    }

    // ---- B-fragments: h1 = relu(W1^T tp + b1), Dekker split, frag order
    u32x4 Bh[4], Bl[4];
    const float* __restrict__ w1a = W1 + i * 128;
    const float* __restrict__ w1b = w1a + 64;
    const float* __restrict__ bb1 = b1 + i * 64;
#pragma unroll
    for (int s = 0; s < 4; ++s) {
#pragma unroll
      for (int q = 0; q < 2; ++q) {
        const int k0 = 4 * h + q * 8 + 16 * s;
        f32x4 wa = *reinterpret_cast<const f32x4*>(w1a + k0);
        f32x4 wb = *reinterpret_cast<const f32x4*>(w1b + k0);
        f32x4 bv = *reinterpret_cast<const f32x4*>(bb1 + k0);
        float h0  = fmaxf(fmaf(tp.x, wa[0], fmaf(tp.y, wb[0], bv[0])), 0.f);
        float h1v = fmaxf(fmaf(tp.x, wa[1], fmaf(tp.y, wb[1], bv[1])), 0.f);
        float h2v = fmaxf(fmaf(tp.x, wa[2], fmaf(tp.y, wb[2], bv[2])), 0.f);
        float h3v = fmaxf(fmaf(tp.x, wa[3], fmaf(tp.y, wb[3], bv[3])), 0.f);
        uint32_t p0 = cvtpk(h0, h1v), p1 = cvtpk(h2v, h3v);
        float l0 = h0  - __builtin_bit_cast(float, p0 << 16);
        float l1 = h1v - __builtin_bit_cast(float, p0 & 0xffff0000u);
        float l2 = h2v - __builtin_bit_cast(float, p1 << 16);
        float l3 = h3v - __builtin_bit_cast(float, p1 & 0xffff0000u);
        Bh[s][q * 2 + 0] = p0;
        Bh[s][q * 2 + 1] = p1;
        Bl[s][q * 2 + 0] = cvtpk(l0, l1);
        Bl[s][q * 2 + 1] = cvtpk(l2, l3);
      }
    }

    // ---- hoist epilogue loads; latency hides under the MFMA chain
    f32x4 ebv[8], ewv[8];               // [T*4 + p]
#pragma unroll
    for (int T = 0; T < 2; ++T)
#pragma unroll
      for (int p = 0; p < 4; ++p) {
        ebv[T * 4 + p] = *reinterpret_cast<const f32x4*>(b2 + i * 64 + T * 32 + 4 * h + p * 8);
        ewv[T * 4 + p] = *reinterpret_cast<const f32x4*>(W3 + i * 64 + T * 32 + 4 * h + p * 8);
      }
    const float compv = comp[(int)g_gas[i] * B + row];
    const float b3v   = b3[i];

    // ---- MFMA: acc[T] = Ah.Bh + Ah.Bl + Al.Bh ; A from LDS
    f32x16 acc0, acc1;
#pragma unroll
    for (int r = 0; r < 16; ++r) { acc0[r] = 0.f; acc1[r] = 0.f; }
#pragma unroll
    for (int s = 0; s < 4; ++s) {
      u32x4 Ah0 = a_lds[cur][(0 * 4 + s) * 64 + l];
      u32x4 Ah1 = a_lds[cur][(1 * 4 + s) * 64 + l];
      u32x4 Al0 = a_lds[cur][(2 * 4 + s) * 64 + l];
      u32x4 Al1 = a_lds[cur][(3 * 4 + s) * 64 + l];
      short8 bh = __builtin_bit_cast(short8, Bh[s]);
      short8 bl = __builtin_bit_cast(short8, Bl[s]);
      acc0 = __builtin_amdgcn_mfma_f32_32x32x16_bf16(__builtin_bit_cast(short8, Ah0), bh, acc0, 0, 0, 0);
      acc1 = __builtin_amdgcn_mfma_f32_32x32x16_bf16(__builtin_bit_cast(short8, Ah1), bh, acc1, 0, 0, 0);
      acc0 = __builtin_amdgcn_mfma_f32_32x32x16_bf16(__builtin_bit_cast(short8, Ah0), bl, acc0, 0, 0, 0);
      acc1 = __builtin_amdgcn_mfma_f32_32x32x16_bf16(__builtin_bit_cast(short8, Ah1), bl, acc1, 0, 0, 0);
      acc0 = __builtin_amdgcn_mfma_f32_32x32x16_bf16(__builtin_bit_cast(short8, Al0), bh, acc0, 0, 0, 0);
      acc1 = __builtin_amdgcn_mfma_f32_32x32x16_bf16(__builtin_bit_cast(short8, Al1), bh, acc1, 0, 0, 0);
    }

    // ---- epilogue: ke = relu( sum_m relu(h2[m]+b2[m]) * w3[m] + b3 )
    float kpa = 0.f, kpb = 0.f;
#pragma unroll
    for (int T = 0; T < 2; ++T)
#pragma unroll
      for (int p = 0; p < 4; ++p) {
        f32x4 bv  = ebv[T * 4 + p];
        f32x4 wvv = ewv[T * 4 + p];
#pragma unroll
        for (int j = 0; j < 4; ++j) {
          float v = fmaxf((T ? acc1[p * 4 + j] : acc0[p * 4 + j]) + bv[j], 0.f);
          if (p & 1) kpb = fmaf(v, wvv[j], kpb);
          else       kpa = fmaf(v, wvv[j], kpa);
        }
      }
    float kp = kpa + kpb;
    kp += __shfl_xor(kp, 32);
    const float ke  = fmaxf(kp + b3v, 0.f);
    const float tau = ke * compv;

    if (l < 32) {
      float* cp = &chan[0][w * 32 + ln];
      cp[128 * (int)g_ch0[i]] += tau;
      const int c1 = g_ch1[i];
      if (c1 >= 0) cp[128 * c1] += tau;
    }

    // ---- commit prefetched A for net i+1 (waits on st* loads here)
    if (i < 75) {
      a_lds[cur ^ 1][(4 * w + 0) * 64 + l] = st0;
      a_lds[cur ^ 1][(4 * w + 1) * 64 + l] = st1;
      a_lds[cur ^ 1][(4 * w + 2) * 64 + l] = st2;
      a_lds[cur ^ 1][(4 * w + 3) * 64 + l] = st3;
    }
    __syncthreads();
  }

  // ---- combine + lw/iw heads (30 channels x 128 rows)
  for (int idx = tid; idx < 30 * 128; idx += 256) {
    const int c = idx >> 7, rl = idx & 127;
    const int r = rowBase + rl;
    out[c * B + r] = chan[c][rl];
    const float lw = fmaxf(fmaf(null_lw[r], W_lw[c], b_lw[c]), 0.f) * comp[6 * B + r];
    const float iw = fmaxf(fmaf(null_iw[r], W_iw[c], b_iw[c]), 0.f) * comp[7 * B + r];
    out[(30 + c) * B + r] = lw;
    out[(60 + c) * B + r] = iw;
  }
}

extern "C" void kernel_launch(void* const* d_in, const int* in_sizes, int n_in,
                              void* d_out, int out_size, void* d_ws, size_t ws_size,
                              hipStream_t stream)
{
  const float* t_p     = (const float*)d_in[0];
  const float* comp    = (const float*)d_in[1];
  const float* null_lw = (const float*)d_in[2];
  const float* null_iw = (const float*)d_in[3];
  const float* W1      = (const float*)d_in[4];
  const float* b1      = (const float*)d_in[5];
  const float* W2      = (const float*)d_in[6];
  const float* b2      = (const float*)d_in[7];
  const float* W3      = (const float*)d_in[8];
  const float* b3      = (const float*)d_in[9];
  const float* W_lw    = (const float*)d_in[10];
  const float* b_lw    = (const float*)d_in[11];
  const float* W_iw    = (const float*)d_in[12];
  const float* b_iw    = (const float*)d_in[13];
  float* out = (float*)d_out;

  const int B = in_sizes[0] / 2;     // 32768
  u32x4* w2f = (u32x4*)d_ws;         // 76 * 16 KB = 1.2 MB

  prep_w2<<<dim3(76), dim3(256), 0, stream>>>(W2, w2f);
  fused_mlp<<<dim3(B / 128), dim3(256), 0, stream>>>(
      t_p, comp, null_lw, null_iw, W1, b1, b2, W3, b3,
      W_lw, b_lw, W_iw, b_iw, w2f, out, B);
}

// Round 11
// 221.984 us; speedup vs baseline: 1.1043x; 1.1043x over previous
//
#include <hip/hip_runtime.h>
#include <stdint.h>

typedef __attribute__((ext_vector_type(8)))  short    short8;
typedef __attribute__((ext_vector_type(16))) float    f32x16;
typedef __attribute__((ext_vector_type(4)))  float    f32x4;
typedef __attribute__((ext_vector_type(4)))  uint32_t u32x4;

// net -> gas id (0..5)
__device__ __constant__ int8_t g_gas[76] = {
  0,0,0,0,0,0,0,0,0,0,0,0,0,0,0,0,0,0,0,0,0,0,0,0,0,0,0,0,0,
  1,1,1,1,1,1,1,1,1,1,1,1,1,
  2,2,2,2,2,2,2,2,2,
  3,3,3,
  4,4,4,4,4,4,4,4,4,
  5,5,5,5,5,5,5,5,5,5,5,5,5
};
// net -> first channel, second channel (-1 = none). Inverse of the SELECT tree.
__device__ __constant__ int8_t g_ch0[76] = {
  0,2,3,4,5,6,7,8,9,10,11,12,13,14,15,16,17,18,19,20,21,22,23,24,25,26,27,28,29,
  0,2,3,18,19,20,21,22,23,26,27,28,29,
  0,2,3,6,7,10,11,14,15,
  0,2,3,
  0,2,3,4,5,8,9,12,13,
  0,2,3,16,17,18,19,20,21,22,23,28,29
};
__device__ __constant__ int8_t g_ch1[76] = {
  1,-1,-1,-1,-1,-1,-1,-1,-1,-1,-1,-1,-1,-1,-1,-1,-1,-1,-1,-1,-1,-1,-1,-1,-1,-1,-1,-1,-1,
  1,-1,-1,-1,-1,-1,-1,-1,-1,-1,-1,-1,-1,
  1,-1,-1,-1,-1,-1,-1,-1,-1,
  1,-1,-1,
  1,-1,-1,-1,-1,-1,-1,-1,-1,
  1,-1,-1,-1,-1,-1,-1,-1,-1,-1,-1,-1,-1
};

// packed f32x2 -> bf16x2 (RTNE), single VALU instruction. Low half = a.
__device__ inline uint32_t cvtpk(float a, float b) {
  uint32_t r;
  asm("v_cvt_pk_bf16_f32 %0, %1, %2" : "=v"(r) : "v"(a), "v"(b));
  return r;
}

// ---------------------------------------------------------------------------
// Prep: split W2 into hi/lo bf16 and lay out as 32x32x16 A-fragments (W2^T).
// Layout: w2f[((term*2 + T)*4 + s)*64 + lane] (u32x4 units), per net i.
//   lane l: m = (l&31) + 32*T,  k = 4*(l>>5) + {0,1,2,3,8,9,10,11} + 16*s
// ---------------------------------------------------------------------------
__global__ __launch_bounds__(256) void prep_w2(const float* __restrict__ W2,
                                               u32x4* __restrict__ w2f)
{
  const int i   = blockIdx.x;
  const int tid = threadIdx.x;
  const int l   = tid & 63;
  const int T   = (tid >> 6) & 1;
  const int sh  = tid >> 7;          // 0,1
  const int h   = l >> 5;
  const int m   = (l & 31) + 32 * T;
  const float* __restrict__ w2 = W2 + i * 4096;   // [k][m] row-major
  u32x4* __restrict__ dst = w2f + (size_t)i * 1024;

#pragma unroll
  for (int ss = 0; ss < 2; ++ss) {
    const int s  = sh * 2 + ss;
    const int kb = 4 * h + 16 * s;
    float x[8];
#pragma unroll
    for (int j = 0; j < 4; ++j) x[j]     = w2[(kb + j) * 64 + m];
#pragma unroll
    for (int j = 0; j < 4; ++j) x[4 + j] = w2[(kb + 8 + j) * 64 + m];
    u32x4 hv, lv;
#pragma unroll
    for (int w = 0; w < 4; ++w) {
      float a = x[2 * w], b = x[2 * w + 1];
      uint32_t hp = cvtpk(a, b);
      float fa = __builtin_bit_cast(float, hp << 16);
      float fb = __builtin_bit_cast(float, hp & 0xffff0000u);
      hv[w] = hp;
      lv[w] = cvtpk(a - fa, b - fb);
    }
    dst[((0 * 2 + T) * 4 + s) * 64 + l] = hv;
    dst[((1 * 2 + T) * 4 + s) * 64 + l] = lv;
  }
}

// A-fragment register set for one net (16 x u32x4 = 64 VGPRs)
struct AFrag {
  u32x4 h0[4], h1[4], l0[4], l1[4];
};

__device__ __forceinline__ void load_frags(const u32x4* __restrict__ base,
                                           int l, AFrag& f) {
#pragma unroll
  for (int s = 0; s < 4; ++s) {
    f.h0[s] = base[(0 * 4 + s) * 64 + l];
    f.h1[s] = base[(1 * 4 + s) * 64 + l];
    f.l0[s] = base[(2 * 4 + s) * 64 + l];
    f.l1[s] = base[(3 * 4 + s) * 64 + l];
  }
}

// One net's full body: prefetch next A-frags, B-prep+MFMA, epilogue, chan acc.
__device__ __forceinline__ void net_body(
    int i, int inext, const u32x4* __restrict__ w2f,
    const float* __restrict__ W1, const float* __restrict__ b1,
    const float* __restrict__ b2, const float* __restrict__ W3,
    const float* __restrict__ b3, const float* __restrict__ comp,
    float2 tp, int row, int B, int l, int h, int ln,
    float* __restrict__ chanCol,   // &chan[g][0][ln], stride 32 per channel
    AFrag& cur, AFrag& nxt)
{
  // 1. prefetch NEXT net's A-fragments (consumed next body -> latency hidden)
  load_frags(w2f + (size_t)inext * 1024, l, nxt);

  // 2. epilogue operands for CURRENT net, issued early (covered by MFMAs)
  f32x4 ebv[8], ewv[8];               // [T*4 + p]
#pragma unroll
  for (int T = 0; T < 2; ++T)
#pragma unroll
    for (int p = 0; p < 4; ++p) {
      ebv[T * 4 + p] = *reinterpret_cast<const f32x4*>(b2 + i * 64 + T * 32 + 4 * h + p * 8);
      ewv[T * 4 + p] = *reinterpret_cast<const f32x4*>(W3 + i * 64 + T * 32 + 4 * h + p * 8);
    }
  const float compv = comp[(int)g_gas[i] * B + row];
  const float b3v   = b3[i];

  // 3. per-s: B-prep (VALU, overlaps loads) then 6 MFMAs from cur regs
  const float* __restrict__ w1a = W1 + i * 128;
  const float* __restrict__ w1b = w1a + 64;
  const float* __restrict__ bb1 = b1 + i * 64;

  f32x16 acc0, acc1;
#pragma unroll
  for (int r = 0; r < 16; ++r) { acc0[r] = 0.f; acc1[r] = 0.f; }

#pragma unroll
  for (int s = 0; s < 4; ++s) {
    u32x4 Bh, Bl;
#pragma unroll
    for (int q = 0; q < 2; ++q) {
      const int k0 = 4 * h + q * 8 + 16 * s;
      f32x4 wa = *reinterpret_cast<const f32x4*>(w1a + k0);
      f32x4 wb = *reinterpret_cast<const f32x4*>(w1b + k0);
      f32x4 bv = *reinterpret_cast<const f32x4*>(bb1 + k0);
      float h0v = fmaxf(fmaf(tp.x, wa[0], fmaf(tp.y, wb[0], bv[0])), 0.f);
      float h1v = fmaxf(fmaf(tp.x, wa[1], fmaf(tp.y, wb[1], bv[1])), 0.f);
      float h2v = fmaxf(fmaf(tp.x, wa[2], fmaf(tp.y, wb[2], bv[2])), 0.f);
      float h3v = fmaxf(fmaf(tp.x, wa[3], fmaf(tp.y, wb[3], bv[3])), 0.f);
      uint32_t p0 = cvtpk(h0v, h1v), p1 = cvtpk(h2v, h3v);
      float l0 = h0v - __builtin_bit_cast(float, p0 << 16);
      float l1 = h1v - __builtin_bit_cast(float, p0 & 0xffff0000u);
      float l2 = h2v - __builtin_bit_cast(float, p1 << 16);
      float l3 = h3v - __builtin_bit_cast(float, p1 & 0xffff0000u);
      Bh[q * 2 + 0] = p0;
      Bh[q * 2 + 1] = p1;
      Bl[q * 2 + 0] = cvtpk(l0, l1);
      Bl[q * 2 + 1] = cvtpk(l2, l3);
    }
    short8 bh = __builtin_bit_cast(short8, Bh);
    short8 bl = __builtin_bit_cast(short8, Bl);
    acc0 = __builtin_amdgcn_mfma_f32_32x32x16_bf16(__builtin_bit_cast(short8, cur.h0[s]), bh, acc0, 0, 0, 0);
    acc1 = __builtin_amdgcn_mfma_f32_32x32x16_bf16(__builtin_bit_cast(short8, cur.h1[s]), bh, acc1, 0, 0, 0);
    acc0 = __builtin_amdgcn_mfma_f32_32x32x16_bf16(__builtin_bit_cast(short8, cur.h0[s]), bl, acc0, 0, 0, 0);
    acc1 = __builtin_amdgcn_mfma_f32_32x32x16_bf16(__builtin_bit_cast(short8, cur.h1[s]), bl, acc1, 0, 0, 0);
    acc0 = __builtin_amdgcn_mfma_f32_32x32x16_bf16(__builtin_bit_cast(short8, cur.l0[s]), bh, acc0, 0, 0, 0);
    acc1 = __builtin_amdgcn_mfma_f32_32x32x16_bf16(__builtin_bit_cast(short8, cur.l1[s]), bh, acc1, 0, 0, 0);
  }

  // 4. epilogue: ke = relu( sum_m relu(h2[m]+b2[m]) * w3[m] + b3 )
  //    lane holds D rows m = (r&3) + 8*(r>>2) + 4*h + 32*T for col ln
  float kpa = 0.f, kpb = 0.f;
#pragma unroll
  for (int T = 0; T < 2; ++T)
#pragma unroll
    for (int p = 0; p < 4; ++p) {
      f32x4 bv  = ebv[T * 4 + p];
      f32x4 wvv = ewv[T * 4 + p];
#pragma unroll
      for (int j = 0; j < 4; ++j) {
        float v = fmaxf((T ? acc1[p * 4 + j] : acc0[p * 4 + j]) + bv[j], 0.f);
        if (p & 1) kpb = fmaf(v, wvv[j], kpb);
        else       kpa = fmaf(v, wvv[j], kpa);
      }
    }
  float kp = kpa + kpb;
  kp += __shfl_xor(kp, 32);
  const float ke  = fmaxf(kp + b3v, 0.f);
  const float tau = ke * compv;

  if (l < 32) {
    chanCol[32 * (int)g_ch0[i]] += tau;
    const int c1 = g_ch1[i];
    if (c1 >= 0) chanCol[32 * c1] += tau;
  }
}

// ---------------------------------------------------------------------------
// Block: 256 thr = 4 waves; wave g handles nets {g, g+4, ...} (19 nets) for
// the same 32 rows. Grid = B/32 = 1024 blocks. A-frags register-prefetched
// one net ahead (ping-pong AFrag pair, 2x-unrolled loop -> no reg copies).
// launch_bounds(256,2): 256-VGPR cap -> no spill (peak live ~210 VGPR).
// ---------------------------------------------------------------------------
__global__ __launch_bounds__(256, 2) void fused_mlp(
    const float* __restrict__ t_p,  const float* __restrict__ comp,
    const float* __restrict__ null_lw, const float* __restrict__ null_iw,
    const float* __restrict__ W1,   const float* __restrict__ b1,
    const float* __restrict__ b2,   const float* __restrict__ W3,
    const float* __restrict__ b3,
    const float* __restrict__ W_lw, const float* __restrict__ b_lw,
    const float* __restrict__ W_iw, const float* __restrict__ b_iw,
    const u32x4* __restrict__ w2f,
    float* __restrict__ out, int B)
{
  __shared__ float chan[4][30][32];
  const int tid = threadIdx.x;
  const int l   = tid & 63;
  const int g   = tid >> 6;          // wave id = net group
  const int h   = l >> 5;
  const int ln  = l & 31;
  const int rowBase = blockIdx.x * 32;
  const int row = rowBase + ln;

  for (int k = tid; k < 4 * 30 * 32; k += 256) ((float*)chan)[k] = 0.f;
  __syncthreads();

  const float2 tp = reinterpret_cast<const float2*>(t_p)[row];
  float* __restrict__ chanCol = &chan[g][0][ln];

  AFrag A0, A1;
  // prologue: load net g's fragments
  load_frags(w2f + (size_t)g * 1024, l, A0);

  // 19 nets: 1 + 9*2, ping-ponging A0/A1 (indices i, i+4 clamped to <=75)
  int i = g;
  net_body(i, i + 4, w2f, W1, b1, b2, W3, b3, comp, tp, row, B, l, h, ln, chanCol, A0, A1);
  i += 4;
#pragma unroll 1
  for (int rep = 0; rep < 9; ++rep) {
    int n1 = (i + 4 <= 75) ? i + 4 : 75;
    net_body(i, n1, w2f, W1, b1, b2, W3, b3, comp, tp, row, B, l, h, ln, chanCol, A1, A0);
    i += 4;
    int n2 = (i + 4 <= 75) ? i + 4 : 75;
    net_body(i, n2, w2f, W1, b1, b2, W3, b3, comp, tp, row, B, l, h, ln, chanCol, A0, A1);
    i += 4;
  }
  __syncthreads();

  // ---- combine + lw/iw heads (30 channels x 32 rows)
  for (int idx = tid; idx < 30 * 32; idx += 256) {
    const int c = idx >> 5, rl = idx & 31;
    const int r = rowBase + rl;
    out[c * B + r] = chan[0][c][rl] + chan[1][c][rl] + chan[2][c][rl] + chan[3][c][rl];
    const float lw = fmaxf(fmaf(null_lw[r], W_lw[c], b_lw[c]), 0.f) * comp[6 * B + r];
    const float iw = fmaxf(fmaf(null_iw[r], W_iw[c], b_iw[c]), 0.f) * comp[7 * B + r];
    out[(30 + c) * B + r] = lw;
    out[(60 + c) * B + r] = iw;
  }
}

extern "C" void kernel_launch(void* const* d_in, const int* in_sizes, int n_in,
                              void* d_out, int out_size, void* d_ws, size_t ws_size,
                              hipStream_t stream)
{
  const float* t_p     = (const float*)d_in[0];
  const float* comp    = (const float*)d_in[1];
  const float* null_lw = (const float*)d_in[2];
  const float* null_iw = (const float*)d_in[3];
  const float* W1      = (const float*)d_in[4];
  const float* b1      = (const float*)d_in[5];
  const float* W2      = (const float*)d_in[6];
  const float* b2      = (const float*)d_in[7];
  const float* W3      = (const float*)d_in[8];
  const float* b3      = (const float*)d_in[9];
  const float* W_lw    = (const float*)d_in[10];
  const float* b_lw    = (const float*)d_in[11];
  const float* W_iw    = (const float*)d_in[12];
  const float* b_iw    = (const float*)d_in[13];
  float* out = (float*)d_out;

  const int B = in_sizes[0] / 2;     // 32768
  u32x4* w2f = (u32x4*)d_ws;         // 76 * 16 KB = 1.2 MB

  prep_w2<<<dim3(76), dim3(256), 0, stream>>>(W2, w2f);
  fused_mlp<<<dim3(B / 32), dim3(256), 0, stream>>>(
      t_p, comp, null_lw, null_iw, W1, b1, b2, W3, b3,
      W_lw, b_lw, W_iw, b_iw, w2f, out, B);
}

// Round 14
// 169.848 us; speedup vs baseline: 1.4433x; 1.3070x over previous
//
#include <hip/hip_runtime.h>
#include <stdint.h>

typedef __attribute__((ext_vector_type(8)))  short    short8;
typedef __attribute__((ext_vector_type(16))) float    f32x16;
typedef __attribute__((ext_vector_type(4)))  float    f32x4;
typedef __attribute__((ext_vector_type(4)))  uint32_t u32x4;

// net -> gas id (0..5)
__device__ __constant__ int8_t g_gas[76] = {
  0,0,0,0,0,0,0,0,0,0,0,0,0,0,0,0,0,0,0,0,0,0,0,0,0,0,0,0,0,
  1,1,1,1,1,1,1,1,1,1,1,1,1,
  2,2,2,2,2,2,2,2,2,
  3,3,3,
  4,4,4,4,4,4,4,4,4,
  5,5,5,5,5,5,5,5,5,5,5,5,5
};
// net -> first channel, second channel (-1 = none). Inverse of the SELECT tree.
__device__ __constant__ int8_t g_ch0[76] = {
  0,2,3,4,5,6,7,8,9,10,11,12,13,14,15,16,17,18,19,20,21,22,23,24,25,26,27,28,29,
  0,2,3,18,19,20,21,22,23,26,27,28,29,
  0,2,3,6,7,10,11,14,15,
  0,2,3,
  0,2,3,4,5,8,9,12,13,
  0,2,3,16,17,18,19,20,21,22,23,28,29
};
__device__ __constant__ int8_t g_ch1[76] = {
  1,-1,-1,-1,-1,-1,-1,-1,-1,-1,-1,-1,-1,-1,-1,-1,-1,-1,-1,-1,-1,-1,-1,-1,-1,-1,-1,-1,-1,
  1,-1,-1,-1,-1,-1,-1,-1,-1,-1,-1,-1,-1,
  1,-1,-1,-1,-1,-1,-1,-1,-1,
  1,-1,-1,
  1,-1,-1,-1,-1,-1,-1,-1,-1,
  1,-1,-1,-1,-1,-1,-1,-1,-1,-1,-1,-1,-1
};

// packed f32x2 -> bf16x2 (RTNE), single VALU instruction. Low half = a.
__device__ inline uint32_t cvtpk(float a, float b) {
  uint32_t r;
  asm("v_cvt_pk_bf16_f32 %0, %1, %2" : "=v"(r) : "v"(a), "v"(b));
  return r;
}

// ---------------------------------------------------------------------------
// Prep: split W2 into hi/lo bf16 and lay out as 32x32x16 A-fragments (W2^T).
// Layout: w2f[((term*2 + T)*4 + s)*64 + lane] (u32x4 units), per net i.
//   lane l: m = (l&31) + 32*T,  k = 4*(l>>5) + {0,1,2,3,8,9,10,11} + 16*s
// ---------------------------------------------------------------------------
__global__ __launch_bounds__(256) void prep_w2(const float* __restrict__ W2,
                                               u32x4* __restrict__ w2f)
{
  const int i   = blockIdx.x;
  const int tid = threadIdx.x;
  const int l   = tid & 63;
  const int T   = (tid >> 6) & 1;
  const int sh  = tid >> 7;          // 0,1
  const int h   = l >> 5;
  const int m   = (l & 31) + 32 * T;
  const float* __restrict__ w2 = W2 + i * 4096;   // [k][m] row-major
  u32x4* __restrict__ dst = w2f + (size_t)i * 1024;

#pragma unroll
  for (int ss = 0; ss < 2; ++ss) {
    const int s  = sh * 2 + ss;
    const int kb = 4 * h + 16 * s;
    float x[8];
#pragma unroll
    for (int j = 0; j < 4; ++j) x[j]     = w2[(kb + j) * 64 + m];
#pragma unroll
    for (int j = 0; j < 4; ++j) x[4 + j] = w2[(kb + 8 + j) * 64 + m];
    u32x4 hv, lv;
#pragma unroll
    for (int w = 0; w < 4; ++w) {
      float a = x[2 * w], b = x[2 * w + 1];
      uint32_t hp = cvtpk(a, b);
      float fa = __builtin_bit_cast(float, hp << 16);
      float fb = __builtin_bit_cast(float, hp & 0xffff0000u);
      hv[w] = hp;
      lv[w] = cvtpk(a - fa, b - fb);
    }
    dst[((0 * 2 + T) * 4 + s) * 64 + l] = hv;
    dst[((1 * 2 + T) * 4 + s) * 64 + l] = lv;
  }
}

// Dekker-split one 4-wide h1 vector; returns (hi0, hi1, lo0, lo1) packed.
__device__ __forceinline__ u32x4 split4(float a, float b, float c, float d) {
  uint32_t hi0 = cvtpk(a, b);
  uint32_t hi1 = cvtpk(c, d);
  float r0 = a - __builtin_bit_cast(float, hi0 << 16);
  float r1 = b - __builtin_bit_cast(float, hi0 & 0xffff0000u);
  float r2 = c - __builtin_bit_cast(float, hi1 << 16);
  float r3 = d - __builtin_bit_cast(float, hi1 & 0xffff0000u);
  u32x4 r;
  r[0] = hi0; r[1] = hi1;
  r[2] = cvtpk(r0, r1); r[3] = cvtpk(r2, r3);
  return r;
}

// ---------------------------------------------------------------------------
// Fused MLP + channel combine, 64 rows per wave (2 column-sets sharing all
// weight loads). Block: 256 thr = 4 waves; wave g handles nets {g, g+4, ...}
// (19 nets) for the same 64 rows. Grid = B/64 = 512 blocks -> 2 blocks/CU.
// A-frag bytes per row HALVED vs the 32-row version (arithmetic intensity 2x).
// ---------------------------------------------------------------------------
__global__ __launch_bounds__(256, 2) void fused_mlp(
    const float* __restrict__ t_p,  const float* __restrict__ comp,
    const float* __restrict__ null_lw, const float* __restrict__ null_iw,
    const float* __restrict__ W1,   const float* __restrict__ b1,
    const float* __restrict__ b2,   const float* __restrict__ W3,
    const float* __restrict__ b3,
    const float* __restrict__ W_lw, const float* __restrict__ b_lw,
    const float* __restrict__ W_iw, const float* __restrict__ b_iw,
    const u32x4* __restrict__ w2f,
    float* __restrict__ out, int B)
{
  __shared__ float chan[4][30][64];   // 30 KB
  const int tid = threadIdx.x;
  const int l   = tid & 63;
  const int g   = tid >> 6;          // wave id = net group
  const int h   = l >> 5;
  const int ln  = l & 31;
  const int rowBase = blockIdx.x * 64;
  const int row0 = rowBase + ln;       // column-set 0
  const int row1 = rowBase + 32 + ln;  // column-set 1

  for (int k = tid; k < 4 * 30 * 64; k += 256) ((float*)chan)[k] = 0.f;
  __syncthreads();

  const float2 tp0 = reinterpret_cast<const float2*>(t_p)[row0];
  const float2 tp1 = reinterpret_cast<const float2*>(t_p)[row1];
  float* __restrict__ chanBase = &chan[g][0][0];

#pragma unroll 1
  for (int i = g; i < 76; i += 4) {
    const u32x4* __restrict__ pnet = w2f + (size_t)i * 1024;
    const float* __restrict__ w1a = W1 + i * 128;
    const float* __restrict__ w1b = w1a + 64;
    const float* __restrict__ bb1 = b1 + i * 64;

    f32x16 a00, a10, a01, a11;   // acc[T][set]
#pragma unroll
    for (int r = 0; r < 16; ++r) { a00[r] = 0.f; a10[r] = 0.f; a01[r] = 0.f; a11[r] = 0.f; }

#pragma unroll
    for (int s = 0; s < 4; ++s) {
      // A-fragments for this s (shared by both column-sets)
      u32x4 Ah0 = pnet[(0 * 4 + s) * 64 + l];
      u32x4 Ah1 = pnet[(1 * 4 + s) * 64 + l];
      u32x4 Al0 = pnet[(2 * 4 + s) * 64 + l];
      u32x4 Al1 = pnet[(3 * 4 + s) * 64 + l];

      // B-prep for both sets; weight loads shared
      u32x4 B0h, B0l, B1h, B1l;
#pragma unroll
      for (int q = 0; q < 2; ++q) {
        const int k0 = 4 * h + q * 8 + 16 * s;
        f32x4 wa = *reinterpret_cast<const f32x4*>(w1a + k0);
        f32x4 wb = *reinterpret_cast<const f32x4*>(w1b + k0);
        f32x4 bv = *reinterpret_cast<const f32x4*>(bb1 + k0);
        float u0 = fmaxf(fmaf(tp0.x, wa[0], fmaf(tp0.y, wb[0], bv[0])), 0.f);
        float u1 = fmaxf(fmaf(tp0.x, wa[1], fmaf(tp0.y, wb[1], bv[1])), 0.f);
        float u2 = fmaxf(fmaf(tp0.x, wa[2], fmaf(tp0.y, wb[2], bv[2])), 0.f);
        float u3 = fmaxf(fmaf(tp0.x, wa[3], fmaf(tp0.y, wb[3], bv[3])), 0.f);
        u32x4 s0 = split4(u0, u1, u2, u3);
        B0h[q*2] = s0[0]; B0h[q*2+1] = s0[1];
        B0l[q*2] = s0[2]; B0l[q*2+1] = s0[3];
        float v0 = fmaxf(fmaf(tp1.x, wa[0], fmaf(tp1.y, wb[0], bv[0])), 0.f);
        float v1 = fmaxf(fmaf(tp1.x, wa[1], fmaf(tp1.y, wb[1], bv[1])), 0.f);
        float v2 = fmaxf(fmaf(tp1.x, wa[2], fmaf(tp1.y, wb[2], bv[2])), 0.f);
        float v3 = fmaxf(fmaf(tp1.x, wa[3], fmaf(tp1.y, wb[3], bv[3])), 0.f);
        u32x4 s1 = split4(v0, v1, v2, v3);
        B1h[q*2] = s1[0]; B1h[q*2+1] = s1[1];
        B1l[q*2] = s1[2]; B1l[q*2+1] = s1[3];
      }
      short8 b0h = __builtin_bit_cast(short8, B0h);
      short8 b0l = __builtin_bit_cast(short8, B0l);
      short8 b1h = __builtin_bit_cast(short8, B1h);
      short8 b1lv = __builtin_bit_cast(short8, B1l);
      short8 ah0 = __builtin_bit_cast(short8, Ah0);
      short8 ah1 = __builtin_bit_cast(short8, Ah1);
      short8 al0 = __builtin_bit_cast(short8, Al0);
      short8 al1 = __builtin_bit_cast(short8, Al1);
      // set 0
      a00 = __builtin_amdgcn_mfma_f32_32x32x16_bf16(ah0, b0h, a00, 0, 0, 0);
      a10 = __builtin_amdgcn_mfma_f32_32x32x16_bf16(ah1, b0h, a10, 0, 0, 0);
      a00 = __builtin_amdgcn_mfma_f32_32x32x16_bf16(ah0, b0l, a00, 0, 0, 0);
      a10 = __builtin_amdgcn_mfma_f32_32x32x16_bf16(ah1, b0l, a10, 0, 0, 0);
      a00 = __builtin_amdgcn_mfma_f32_32x32x16_bf16(al0, b0h, a00, 0, 0, 0);
      a10 = __builtin_amdgcn_mfma_f32_32x32x16_bf16(al1, b0h, a10, 0, 0, 0);
      // set 1
      a01 = __builtin_amdgcn_mfma_f32_32x32x16_bf16(ah0, b1h, a01, 0, 0, 0);
      a11 = __builtin_amdgcn_mfma_f32_32x32x16_bf16(ah1, b1h, a11, 0, 0, 0);
      a01 = __builtin_amdgcn_mfma_f32_32x32x16_bf16(ah0, b1lv, a01, 0, 0, 0);
      a11 = __builtin_amdgcn_mfma_f32_32x32x16_bf16(ah1, b1lv, a11, 0, 0, 0);
      a01 = __builtin_amdgcn_mfma_f32_32x32x16_bf16(al0, b1h, a01, 0, 0, 0);
      a11 = __builtin_amdgcn_mfma_f32_32x32x16_bf16(al1, b1h, a11, 0, 0, 0);
    }

    // ---- epilogue (weights shared between sets)
    // lane holds D rows m = (r&3) + 8*(r>>2) + 4*h + 32*T for its column
    float kp0a = 0.f, kp0b = 0.f, kp1a = 0.f, kp1b = 0.f;
#pragma unroll
    for (int T = 0; T < 2; ++T)
#pragma unroll
      for (int p = 0; p < 4; ++p) {
        f32x4 bv  = *reinterpret_cast<const f32x4*>(b2 + i * 64 + T * 32 + 4 * h + p * 8);
        f32x4 wvv = *reinterpret_cast<const f32x4*>(W3 + i * 64 + T * 32 + 4 * h + p * 8);
#pragma unroll
        for (int j = 0; j < 4; ++j) {
          float v0 = fmaxf((T ? a10[p * 4 + j] : a00[p * 4 + j]) + bv[j], 0.f);
          float v1 = fmaxf((T ? a11[p * 4 + j] : a01[p * 4 + j]) + bv[j], 0.f);
          if (p & 1) { kp0b = fmaf(v0, wvv[j], kp0b); kp1b = fmaf(v1, wvv[j], kp1b); }
          else       { kp0a = fmaf(v0, wvv[j], kp0a); kp1a = fmaf(v1, wvv[j], kp1a); }
        }
      }
    float kp0 = kp0a + kp0b;
    float kp1 = kp1a + kp1b;
    kp0 += __shfl_xor(kp0, 32);
    kp1 += __shfl_xor(kp1, 32);
    const float b3v = b3[i];
    const int   gas = (int)g_gas[i];
    // low lanes commit set 0 (rows rowBase+ln), high lanes set 1 (rowBase+32+ln)
    const float ke  = fmaxf((l < 32 ? kp0 : kp1) + b3v, 0.f);
    const float cv  = comp[gas * B + rowBase + l];   // l == set*32 + ln
    const float tau = ke * cv;
    float* cp = chanBase + l;                        // chan[g][0][l]
    cp[64 * (int)g_ch0[i]] += tau;
    const int c1 = g_ch1[i];
    if (c1 >= 0) cp[64 * c1] += tau;
  }
  __syncthreads();

  // ---- combine + lw/iw heads (30 channels x 64 rows)
  for (int idx = tid; idx < 30 * 64; idx += 256) {
    const int c = idx >> 6, rl = idx & 63;
    const int r = rowBase + rl;
    out[c * B + r] = chan[0][c][rl] + chan[1][c][rl] + chan[2][c][rl] + chan[3][c][rl];
    const float lw = fmaxf(fmaf(null_lw[r], W_lw[c], b_lw[c]), 0.f) * comp[6 * B + r];
    const float iw = fmaxf(fmaf(null_iw[r], W_iw[c], b_iw[c]), 0.f) * comp[7 * B + r];
    out[(30 + c) * B + r] = lw;
    out[(60 + c) * B + r] = iw;
  }
}

extern "C" void kernel_launch(void* const* d_in, const int* in_sizes, int n_in,
                              void* d_out, int out_size, void* d_ws, size_t ws_size,
                              hipStream_t stream)
{
  const float* t_p     = (const float*)d_in[0];
  const float* comp    = (const float*)d_in[1];
  const float* null_lw = (const float*)d_in[2];
  const float* null_iw = (const float*)d_in[3];
  const float* W1      = (const float*)d_in[4];
  const float* b1      = (const float*)d_in[5];
  const float* W2      = (const float*)d_in[6];
  const float* b2      = (const float*)d_in[7];
  const float* W3      = (const float*)d_in[8];
  const float* b3      = (const float*)d_in[9];
  const float* W_lw    = (const float*)d_in[10];
  const float* b_lw    = (const float*)d_in[11];
  const float* W_iw    = (const float*)d_in[12];
  const float* b_iw    = (const float*)d_in[13];
  float* out = (float*)d_out;

  const int B = in_sizes[0] / 2;     // 32768
  u32x4* w2f = (u32x4*)d_ws;         // 76 * 16 KB = 1.2 MB

  prep_w2<<<dim3(76), dim3(256), 0, stream>>>(W2, w2f);
  fused_mlp<<<dim3(B / 64), dim3(256), 0, stream>>>(
      t_p, comp, null_lw, null_iw, W1, b1, b2, W3, b3,
      W_lw, b_lw, W_iw, b_iw, w2f, out, B);
}